// Round 17
// baseline (3873.058 us; speedup 1.0000x reference)
//
#include <hip/hip_runtime.h>
#include <hip/hip_bf16.h>
#include <math.h>
#include <stdint.h>

#define D_IN  2048
#define H_MID 1024
#define E_OUT 64

// Block FMA-contraction across this value (keeps separate mul/add rounding).
#define NOFMA(x) asm volatile("" : "+v"(x))

// ------- GEMM1: hpre = x @ W1 (fp32, KC=512 k-blocking) — VERIFIED R9 -------
// K=2048 -> blocks [512,512,512,512]; per element each block is a dependent
// ascending-k fp32 FMA chain from 0; block partials added sequentially
// ((p0+p1)+p2)+p3 via RMW flush to hpre at KC boundaries (bit-exact, R13).
// R17: 64x128 tile, 4x8 micro-tile, BK=16, (256,4) -> 4 blocks/CU.
// R16 measured VGPR=52 at cap 84 -> natural demand 52 < the 64-VGPR cap of
// (256,4), so no spill and one more resident block for stall hiding.
__global__ __launch_bounds__(256, 4)
void gemm1_kernel(const float* __restrict__ x, const float* __restrict__ W1,
                  float* __restrict__ hpre)
{
    __shared__ __align__(16) float As[2][16][68];    // [k][m], +4 pad (8.7KB)
    __shared__ __align__(16) float Bs[2][16][128];   // [k][n]       (16.4KB)

    const int t  = threadIdx.x;
    const int tx = t & 15, ty = t >> 4;              // tx: 8-col group, ty: 4-row
    const int row0 = blockIdx.y * 64;
    const int col0 = blockIdx.x * 128;

    float acc[4][8];     // current KC-block partial chain (only accumulator)
#pragma unroll
    for (int i = 0; i < 4; ++i)
#pragma unroll
        for (int j = 0; j < 8; ++j) acc[i][j] = 0.0f;

    // A staging: thread t covers row t>>2 (0..63), k-chunk (t&3)*4
    const int ar  = t >> 2;
    const int ac4 = (t & 3) * 4;
    const float* xA = x + (size_t)(row0 + ar) * D_IN + ac4;
    // B staging: thread t covers rows (t>>5) and 8+(t>>5), cols (t&31)*4
    const int bk = t >> 5;
    const int bn = (t & 31) * 4;
    const float* wB = W1 + (size_t)bk * H_MID + col0 + bn;

    float4 aR0, bR0, bR1;

    // ---- prologue: stage tile kt=0 into buffer 0 ----
    aR0 = *(const float4*)(xA);
    bR0 = *(const float4*)(wB);
    bR1 = *(const float4*)(wB + (size_t)8 * H_MID);
    As[0][ac4 + 0][ar] = aR0.x; As[0][ac4 + 1][ar] = aR0.y;
    As[0][ac4 + 2][ar] = aR0.z; As[0][ac4 + 3][ar] = aR0.w;
    *(float4*)&Bs[0][bk][bn]     = bR0;
    *(float4*)&Bs[0][8 + bk][bn] = bR1;

    const int NT = D_IN / 16;      // 128 tiles of BK=16
    for (int kt = 0; kt < NT; ++kt) {
        const int cur = kt & 1;
        __syncthreads();
        if (kt + 1 < NT) {
            aR0 = *(const float4*)(xA + (kt + 1) * 16);
            const float* wb = wB + (size_t)(kt + 1) * 16 * H_MID;
            bR0 = *(const float4*)(wb);
            bR1 = *(const float4*)(wb + (size_t)8 * H_MID);
        }
#pragma unroll
        for (int kk = 0; kk < 16; ++kk) {
            const float4 a0 = *(const float4*)&As[cur][kk][ty * 4];
            const float4 b0 = *(const float4*)&Bs[cur][kk][tx * 4];
            const float4 b1 = *(const float4*)&Bs[cur][kk][64 + tx * 4];
            const float av[4] = {a0.x, a0.y, a0.z, a0.w};
            const float bv[8] = {b0.x, b0.y, b0.z, b0.w, b1.x, b1.y, b1.z, b1.w};
#pragma unroll
            for (int i = 0; i < 4; ++i)
#pragma unroll
                for (int j = 0; j < 8; ++j)
                    acc[i][j] = __builtin_fmaf(av[i], bv[j], acc[i][j]);
        }
        // KC=512 boundary: kt = 31, 63, 95, 127.  Flush partial to hpre:
        // first boundary stores, later ones load+add+store (C += partial,
        // same sequential order as a register acc_t — bit-exact).
        if ((kt & 31) == 31) {
            const bool first = (kt == 31);
#pragma unroll
            for (int i = 0; i < 4; ++i) {
                const int rr = ty * 4 + i;
                float* cp = hpre + (size_t)(row0 + rr) * H_MID + col0;
                float4 c0, c1;
                c0.x = acc[i][0]; c0.y = acc[i][1];
                c0.z = acc[i][2]; c0.w = acc[i][3];
                c1.x = acc[i][4]; c1.y = acc[i][5];
                c1.z = acc[i][6]; c1.w = acc[i][7];
                if (!first) {
                    const float4 o0 = *(const float4*)(cp + tx * 4);
                    const float4 o1 = *(const float4*)(cp + 64 + tx * 4);
                    c0.x = o0.x + c0.x; c0.y = o0.y + c0.y;
                    c0.z = o0.z + c0.z; c0.w = o0.w + c0.w;
                    c1.x = o1.x + c1.x; c1.y = o1.y + c1.y;
                    c1.z = o1.z + c1.z; c1.w = o1.w + c1.w;
                }
                *(float4*)(cp + tx * 4)      = c0;
                *(float4*)(cp + 64 + tx * 4) = c1;
#pragma unroll
                for (int j = 0; j < 8; ++j) acc[i][j] = 0.0f;
            }
        }
        if (kt + 1 < NT) {
            const int nb = cur ^ 1;
            As[nb][ac4 + 0][ar] = aR0.x; As[nb][ac4 + 1][ar] = aR0.y;
            As[nb][ac4 + 2][ar] = aR0.z; As[nb][ac4 + 3][ar] = aR0.w;
            *(float4*)&Bs[nb][bk][bn]     = bR0;
            *(float4*)&Bs[nb][8 + bk][bn] = bR1;
        }
    }
    // no epilogue: the kt==127 flush wrote the final hpre values
}

// ---- wave-parallel numpy pairwise-64: gather g[8], serial 7-chain, tree ----
__device__ __forceinline__ float np64_chain_tree(const float* g)
{
    float r = g[0];
#pragma unroll
    for (int i = 1; i < 8; ++i) r += g[i];
#pragma unroll
    for (int d = 1; d <= 4; d <<= 1) r += __shfl_xor(r, d);
    return r;
}

// -------- tail v3: wave-parallel, bit-identical arithmetic to R9 ------------
// block = 256 threads (4 waves), 8 rows; wave w owns rows w and w+4.
__global__ __launch_bounds__(256, 3)
void tail_v3_kernel(const float* __restrict__ hpre,
                    const float* __restrict__ b1v, const float* __restrict__ g1v,
                    const float* __restrict__ be1v,
                    const float* __restrict__ W2,
                    const float* __restrict__ b2v, const float* __restrict__ g2v,
                    const float* __restrict__ be2v,
                    float* __restrict__ wout, float* __restrict__ iout,
                    int rowBase)
{
    __shared__ float hs[8][1024];                  // 32 KB
    __shared__ __align__(16) float w2s[64][64];    // 16 KB

    const int t    = threadIdx.x;
    const int lane = t & 63;
    const int w    = t >> 6;
    const int q    = lane >> 3;     // base128 block (LN1 accumulators)
    const int j    = lane & 7;      // accumulator index within block
    const int r0   = blockIdx.x * 8;

    // ---- Phase A: LN1 + ReLU, rows w and w+4 -------------------------------
#pragma unroll
    for (int half = 0; half < 2; ++half) {
        const int rr = w + half * 4;
        const float* hp = hpre + (size_t)(r0 + rr) * H_MID;
        float v[16];
#pragma unroll
        for (int i = 0; i < 16; ++i) {
            const int idx = q * 128 + i * 8 + j;
            v[i] = hp[idx] + b1v[idx];            // fp32 broadcast add (A1)
        }
        float r = v[0];
#pragma unroll
        for (int i = 1; i < 16; ++i) r += v[i];   // serial 15-add chain
#pragma unroll
        for (int d = 1; d <= 32; d <<= 1) r += __shfl_xor(r, d);
        const float mu = r * (1.0f / 1024.0f);

        float r2;
        {
            float d0 = v[0] - mu; float sq = d0 * d0; NOFMA(sq); r2 = sq;
#pragma unroll
            for (int i = 1; i < 16; ++i) {
                float dd = v[i] - mu; float sq2 = dd * dd; NOFMA(sq2);
                r2 += sq2;
            }
        }
#pragma unroll
        for (int d = 1; d <= 32; d <<= 1) r2 += __shfl_xor(r2, d);
        const float var = r2 * (1.0f / 1024.0f);
        const float rs  = 1.0f / sqrtf(var + 1e-5f);

#pragma unroll
        for (int i = 0; i < 16; ++i) {
            const int idx = q * 128 + i * 8 + j;
            const float t1 = v[i] - mu;
            float t2 = t1 * rs;        NOFMA(t2);
            float t3 = t2 * g1v[idx];  NOFMA(t3);
            const float t4 = t3 + be1v[idx];
            hs[rr][idx] = fmaxf(t4, 0.0f);
        }
    }
    __syncthreads();

    // ---- Phase B: GEMM2, k-blocks [512,512], 2 independent rows per wave ---
    float ya_t = 0.0f, ya_p = 0.0f, yb_t = 0.0f, yb_p = 0.0f;
    const int ra = w, rb = w + 4;
    for (int c = 0; c < 16; ++c) {                 // 16 chunks of 64
        const int jc = c * 64;
#pragma unroll
        for (int p = 0; p < 4; ++p) {
            const int idx4 = p * 256 + t;          // 1024 float4 = 64x64
            const int kk = idx4 >> 4;
            const int nn = (idx4 & 15) * 4;
            *(float4*)&w2s[kk][nn] =
                *(const float4*)(W2 + (size_t)(jc + kk) * E_OUT + nn);
        }
        __syncthreads();
#pragma unroll 8
        for (int jj = 0; jj < 64; ++jj) {
            const float wv2 = w2s[jj][lane];
            ya_p = __builtin_fmaf(hs[ra][jc + jj], wv2, ya_p);
            yb_p = __builtin_fmaf(hs[rb][jc + jj], wv2, yb_p);
        }
        if (c == 7 || c == 15) {                   // block ends k=512, k=1024
            ya_t += ya_p; ya_p = 0.0f;
            yb_t += yb_p; yb_p = 0.0f;
        }
        __syncthreads();
    }
    const float ya = ya_t + b2v[lane];             // b2 added AFTER matmul
    const float yb = yb_t + b2v[lane];

    // ---- Phase C: LN2 -> softmax -> top-8 -> renorm -> scatter (per wave) --
    const float g2l  = g2v[lane];
    const float be2l = be2v[lane];
#pragma unroll
    for (int half = 0; half < 2; ++half) {
        const int   rr = (half == 0) ? ra : rb;
        const float y  = (half == 0) ? ya : yb;

        float g[8];
#pragma unroll
        for (int i = 0; i < 8; ++i) g[i] = __shfl(y, i * 8 + j);
        const float s  = np64_chain_tree(g);
        const float mu = s * (1.0f / 64.0f);
        float gsq[8];
#pragma unroll
        for (int i = 0; i < 8; ++i) {
            float dd = g[i] - mu; float sq = dd * dd; NOFMA(sq);
            gsq[i] = sq;
        }
        const float sv  = np64_chain_tree(gsq);
        const float var = sv * (1.0f / 64.0f);
        const float rs  = 1.0f / sqrtf(var + 1e-5f);

        const float t1 = y - mu;
        float t2 = t1 * rs;   NOFMA(t2);
        float t3 = t2 * g2l;  NOFMA(t3);
        const float lg = t3 + be2l;

        float mx = lg;
#pragma unroll
        for (int d = 1; d <= 32; d <<= 1) mx = fmaxf(mx, __shfl_xor(mx, d));
        const float ex = expf(lg - mx);

        float ge[8];
#pragma unroll
        for (int i = 0; i < 8; ++i) ge[i] = __shfl(ex, i * 8 + j);
        const float den = np64_chain_tree(ge);
        float pb = ex / den;

        // top-8: butterfly argmax (max value, min index) == serial strict-'>'
        float tv[8]; int ti[8];
#pragma unroll
        for (int k = 0; k < 8; ++k) {
            float bv = pb; int bi = lane;
#pragma unroll
            for (int d = 1; d <= 32; d <<= 1) {
                const float ov = __shfl_xor(bv, d);
                const int   oi = __shfl_xor(bi, d);
                if (ov > bv || (ov == bv && oi < bi)) { bv = ov; bi = oi; }
            }
            tv[k] = bv; ti[k] = bi;
            if (lane == bi) pb = -1.0f;
        }
        float s8 = 0.0f;
#pragma unroll
        for (int k = 0; k < 8; ++k) s8 += tv[k];   // serial fp32 sum of 8
        const float dnm = s8 + 1e-8f;

        float wv = 0.0f;
#pragma unroll
        for (int k = 0; k < 8; ++k) if (ti[k] == lane) wv = tv[k] / dnm;

        const size_t grow = (size_t)rowBase + r0 + rr;
        wout[grow * 64 + lane] = wv;
#pragma unroll
        for (int k = 0; k < 8; ++k)
            if (lane == k) iout[grow * 8 + k] = (float)ti[k];
    }
}

extern "C" void kernel_launch(void* const* d_in, const int* in_sizes, int n_in,
                              void* d_out, int out_size, void* d_ws, size_t ws_size,
                              hipStream_t stream)
{
    (void)n_in; (void)out_size;
    const float* x   = (const float*)d_in[0];
    const float* W1  = (const float*)d_in[1];
    const float* b1  = (const float*)d_in[2];
    const float* g1  = (const float*)d_in[3];
    const float* be1 = (const float*)d_in[4];
    const float* W2  = (const float*)d_in[5];
    const float* b2  = (const float*)d_in[6];
    const float* g2  = (const float*)d_in[7];
    const float* be2 = (const float*)d_in[8];

    const int B = in_sizes[0] / D_IN;
    float* wout = (float*)d_out;
    float* iout = wout + (size_t)B * E_OUT;
    float* hws  = (float*)d_ws;

    size_t cap = ws_size / ((size_t)H_MID * sizeof(float));
    long long ch = (long long)((cap > (size_t)B) ? (size_t)B : cap);
    ch &= ~127LL;
    if (ch < 128) ch = 128;
    const int CH = (int)ch;

    for (int base = 0; base < B; base += CH) {
        int Mc = B - base; if (Mc > CH) Mc = CH;
        dim3 grid1(H_MID / 128, Mc / 64);    // col-block fastest-varying
        gemm1_kernel<<<grid1, 256, 0, stream>>>(x + (size_t)base * D_IN, W1, hws);
        tail_v3_kernel<<<Mc / 8, 256, 0, stream>>>(hws, b1, g1, be1, W2, b2, g2, be2,
                                                   wout, iout, base);
    }
}

// Round 18
// 3861.001 us; speedup vs baseline: 1.0031x; 1.0031x over previous
//
#include <hip/hip_runtime.h>
#include <hip/hip_bf16.h>
#include <math.h>
#include <stdint.h>

#define D_IN  2048
#define H_MID 1024
#define E_OUT 64

// Block FMA-contraction across this value (keeps separate mul/add rounding).
#define NOFMA(x) asm volatile("" : "+v"(x))

// ------- GEMM1: hpre = x @ W1 (fp32, KC=512 k-blocking) — VERIFIED R9 -------
// K=2048 -> blocks [512,512,512,512]; per element each block is a dependent
// ascending-k fp32 FMA chain from 0; block partials added sequentially
// ((p0+p1)+p2)+p3 via RMW flush to hpre at KC boundaries (bit-exact, R13).
// R18: B-panel staged via __builtin_amdgcn_global_load_lds (width=16) —
// B's LDS layout is linear in thread id (offset 16t per 8-row chunk), the
// wave-uniform-base + lane*16 pattern the DMA requires. Removes 2 global->reg
// loads + 2 ds_write_b128 per kt and ~8 staging VGPRs. A keeps reg staging
// (transposed [k][m] layout is not lane-linear). Arithmetic untouched.
__global__ __launch_bounds__(256, 4)
void gemm1_kernel(const float* __restrict__ x, const float* __restrict__ W1,
                  float* __restrict__ hpre)
{
    __shared__ __align__(16) float As[2][16][68];    // [k][m], +4 pad (8.7KB)
    __shared__ __align__(16) float Bs[2][16][128];   // [k][n]       (16.4KB)

    const int t  = threadIdx.x;
    const int tx = t & 15, ty = t >> 4;              // tx: 8-col group, ty: 4-row
    const int row0 = blockIdx.y * 64;
    const int col0 = blockIdx.x * 128;

    float acc[4][8];     // current KC-block partial chain (only accumulator)
#pragma unroll
    for (int i = 0; i < 4; ++i)
#pragma unroll
        for (int j = 0; j < 8; ++j) acc[i][j] = 0.0f;

    // A staging: thread t covers row t>>2 (0..63), k-chunk (t&3)*4
    const int ar  = t >> 2;
    const int ac4 = (t & 3) * 4;
    const float* xA = x + (size_t)(row0 + ar) * D_IN + ac4;
    // B staging: thread t covers rows (t>>5) and 8+(t>>5), cols (t&31)*4
    const int bk = t >> 5;
    const int bn = (t & 31) * 4;
    const float* wB = W1 + (size_t)bk * H_MID + col0 + bn;

    float4 aR0;

    // ---- prologue: stage tile kt=0 into buffer 0 ----
    __builtin_amdgcn_global_load_lds(wB, &Bs[0][bk][bn], 16, 0, 0);
    __builtin_amdgcn_global_load_lds(wB + (size_t)8 * H_MID,
                                     &Bs[0][8 + bk][bn], 16, 0, 0);
    aR0 = *(const float4*)(xA);
    As[0][ac4 + 0][ar] = aR0.x; As[0][ac4 + 1][ar] = aR0.y;
    As[0][ac4 + 2][ar] = aR0.z; As[0][ac4 + 3][ar] = aR0.w;

    const int NT = D_IN / 16;      // 128 tiles of BK=16
    for (int kt = 0; kt < NT; ++kt) {
        const int cur = kt & 1;
        __syncthreads();           // drains vmcnt: B DMA + A ds_write visible
        if (kt + 1 < NT) {
            const int nb = cur ^ 1;
            // issue next B tile straight to LDS (async, other buffer)
            const float* wb = wB + (size_t)(kt + 1) * 16 * H_MID;
            __builtin_amdgcn_global_load_lds(wb, &Bs[nb][bk][bn], 16, 0, 0);
            __builtin_amdgcn_global_load_lds(wb + (size_t)8 * H_MID,
                                             &Bs[nb][8 + bk][bn], 16, 0, 0);
            // A next tile -> regs (transposed ds_write after compute)
            aR0 = *(const float4*)(xA + (kt + 1) * 16);
        }
#pragma unroll
        for (int kk = 0; kk < 16; ++kk) {
            const float4 a0 = *(const float4*)&As[cur][kk][ty * 4];
            const float4 b0 = *(const float4*)&Bs[cur][kk][tx * 4];
            const float4 b1 = *(const float4*)&Bs[cur][kk][64 + tx * 4];
            const float av[4] = {a0.x, a0.y, a0.z, a0.w};
            const float bv[8] = {b0.x, b0.y, b0.z, b0.w, b1.x, b1.y, b1.z, b1.w};
#pragma unroll
            for (int i = 0; i < 4; ++i)
#pragma unroll
                for (int j = 0; j < 8; ++j)
                    acc[i][j] = __builtin_fmaf(av[i], bv[j], acc[i][j]);
        }
        // KC=512 boundary: kt = 31, 63, 95, 127.  Flush partial to hpre:
        // first boundary stores, later ones load+add+store (C += partial,
        // same sequential order as a register acc_t — bit-exact).
        if ((kt & 31) == 31) {
            const bool first = (kt == 31);
#pragma unroll
            for (int i = 0; i < 4; ++i) {
                const int rr = ty * 4 + i;
                float* cp = hpre + (size_t)(row0 + rr) * H_MID + col0;
                float4 c0, c1;
                c0.x = acc[i][0]; c0.y = acc[i][1];
                c0.z = acc[i][2]; c0.w = acc[i][3];
                c1.x = acc[i][4]; c1.y = acc[i][5];
                c1.z = acc[i][6]; c1.w = acc[i][7];
                if (!first) {
                    const float4 o0 = *(const float4*)(cp + tx * 4);
                    const float4 o1 = *(const float4*)(cp + 64 + tx * 4);
                    c0.x = o0.x + c0.x; c0.y = o0.y + c0.y;
                    c0.z = o0.z + c0.z; c0.w = o0.w + c0.w;
                    c1.x = o1.x + c1.x; c1.y = o1.y + c1.y;
                    c1.z = o1.z + c1.z; c1.w = o1.w + c1.w;
                }
                *(float4*)(cp + tx * 4)      = c0;
                *(float4*)(cp + 64 + tx * 4) = c1;
#pragma unroll
                for (int j = 0; j < 8; ++j) acc[i][j] = 0.0f;
            }
        }
        if (kt + 1 < NT) {
            const int nb = cur ^ 1;
            As[nb][ac4 + 0][ar] = aR0.x; As[nb][ac4 + 1][ar] = aR0.y;
            As[nb][ac4 + 2][ar] = aR0.z; As[nb][ac4 + 3][ar] = aR0.w;
        }
    }
    // no epilogue: the kt==127 flush wrote the final hpre values
}

// ---- wave-parallel numpy pairwise-64: gather g[8], serial 7-chain, tree ----
__device__ __forceinline__ float np64_chain_tree(const float* g)
{
    float r = g[0];
#pragma unroll
    for (int i = 1; i < 8; ++i) r += g[i];
#pragma unroll
    for (int d = 1; d <= 4; d <<= 1) r += __shfl_xor(r, d);
    return r;
}

// -------- tail v3: wave-parallel, bit-identical arithmetic to R9 ------------
// block = 256 threads (4 waves), 8 rows; wave w owns rows w and w+4.
__global__ __launch_bounds__(256, 3)
void tail_v3_kernel(const float* __restrict__ hpre,
                    const float* __restrict__ b1v, const float* __restrict__ g1v,
                    const float* __restrict__ be1v,
                    const float* __restrict__ W2,
                    const float* __restrict__ b2v, const float* __restrict__ g2v,
                    const float* __restrict__ be2v,
                    float* __restrict__ wout, float* __restrict__ iout,
                    int rowBase)
{
    __shared__ float hs[8][1024];                  // 32 KB
    __shared__ __align__(16) float w2s[64][64];    // 16 KB

    const int t    = threadIdx.x;
    const int lane = t & 63;
    const int w    = t >> 6;
    const int q    = lane >> 3;     // base128 block (LN1 accumulators)
    const int j    = lane & 7;      // accumulator index within block
    const int r0   = blockIdx.x * 8;

    // ---- Phase A: LN1 + ReLU, rows w and w+4 -------------------------------
#pragma unroll
    for (int half = 0; half < 2; ++half) {
        const int rr = w + half * 4;
        const float* hp = hpre + (size_t)(r0 + rr) * H_MID;
        float v[16];
#pragma unroll
        for (int i = 0; i < 16; ++i) {
            const int idx = q * 128 + i * 8 + j;
            v[i] = hp[idx] + b1v[idx];            // fp32 broadcast add (A1)
        }
        float r = v[0];
#pragma unroll
        for (int i = 1; i < 16; ++i) r += v[i];   // serial 15-add chain
#pragma unroll
        for (int d = 1; d <= 32; d <<= 1) r += __shfl_xor(r, d);
        const float mu = r * (1.0f / 1024.0f);

        float r2;
        {
            float d0 = v[0] - mu; float sq = d0 * d0; NOFMA(sq); r2 = sq;
#pragma unroll
            for (int i = 1; i < 16; ++i) {
                float dd = v[i] - mu; float sq2 = dd * dd; NOFMA(sq2);
                r2 += sq2;
            }
        }
#pragma unroll
        for (int d = 1; d <= 32; d <<= 1) r2 += __shfl_xor(r2, d);
        const float var = r2 * (1.0f / 1024.0f);
        const float rs  = 1.0f / sqrtf(var + 1e-5f);

#pragma unroll
        for (int i = 0; i < 16; ++i) {
            const int idx = q * 128 + i * 8 + j;
            const float t1 = v[i] - mu;
            float t2 = t1 * rs;        NOFMA(t2);
            float t3 = t2 * g1v[idx];  NOFMA(t3);
            const float t4 = t3 + be1v[idx];
            hs[rr][idx] = fmaxf(t4, 0.0f);
        }
    }
    __syncthreads();

    // ---- Phase B: GEMM2, k-blocks [512,512], 2 independent rows per wave ---
    float ya_t = 0.0f, ya_p = 0.0f, yb_t = 0.0f, yb_p = 0.0f;
    const int ra = w, rb = w + 4;
    for (int c = 0; c < 16; ++c) {                 // 16 chunks of 64
        const int jc = c * 64;
#pragma unroll
        for (int p = 0; p < 4; ++p) {
            const int idx4 = p * 256 + t;          // 1024 float4 = 64x64
            const int kk = idx4 >> 4;
            const int nn = (idx4 & 15) * 4;
            *(float4*)&w2s[kk][nn] =
                *(const float4*)(W2 + (size_t)(jc + kk) * E_OUT + nn);
        }
        __syncthreads();
#pragma unroll 8
        for (int jj = 0; jj < 64; ++jj) {
            const float wv2 = w2s[jj][lane];
            ya_p = __builtin_fmaf(hs[ra][jc + jj], wv2, ya_p);
            yb_p = __builtin_fmaf(hs[rb][jc + jj], wv2, yb_p);
        }
        if (c == 7 || c == 15) {                   // block ends k=512, k=1024
            ya_t += ya_p; ya_p = 0.0f;
            yb_t += yb_p; yb_p = 0.0f;
        }
        __syncthreads();
    }
    const float ya = ya_t + b2v[lane];             // b2 added AFTER matmul
    const float yb = yb_t + b2v[lane];

    // ---- Phase C: LN2 -> softmax -> top-8 -> renorm -> scatter (per wave) --
    const float g2l  = g2v[lane];
    const float be2l = be2v[lane];
#pragma unroll
    for (int half = 0; half < 2; ++half) {
        const int   rr = (half == 0) ? ra : rb;
        const float y  = (half == 0) ? ya : yb;

        float g[8];
#pragma unroll
        for (int i = 0; i < 8; ++i) g[i] = __shfl(y, i * 8 + j);
        const float s  = np64_chain_tree(g);
        const float mu = s * (1.0f / 64.0f);
        float gsq[8];
#pragma unroll
        for (int i = 0; i < 8; ++i) {
            float dd = g[i] - mu; float sq = dd * dd; NOFMA(sq);
            gsq[i] = sq;
        }
        const float sv  = np64_chain_tree(gsq);
        const float var = sv * (1.0f / 64.0f);
        const float rs  = 1.0f / sqrtf(var + 1e-5f);

        const float t1 = y - mu;
        float t2 = t1 * rs;   NOFMA(t2);
        float t3 = t2 * g2l;  NOFMA(t3);
        const float lg = t3 + be2l;

        float mx = lg;
#pragma unroll
        for (int d = 1; d <= 32; d <<= 1) mx = fmaxf(mx, __shfl_xor(mx, d));
        const float ex = expf(lg - mx);

        float ge[8];
#pragma unroll
        for (int i = 0; i < 8; ++i) ge[i] = __shfl(ex, i * 8 + j);
        const float den = np64_chain_tree(ge);
        float pb = ex / den;

        // top-8: butterfly argmax (max value, min index) == serial strict-'>'
        float tv[8]; int ti[8];
#pragma unroll
        for (int k = 0; k < 8; ++k) {
            float bv = pb; int bi = lane;
#pragma unroll
            for (int d = 1; d <= 32; d <<= 1) {
                const float ov = __shfl_xor(bv, d);
                const int   oi = __shfl_xor(bi, d);
                if (ov > bv || (ov == bv && oi < bi)) { bv = ov; bi = oi; }
            }
            tv[k] = bv; ti[k] = bi;
            if (lane == bi) pb = -1.0f;
        }
        float s8 = 0.0f;
#pragma unroll
        for (int k = 0; k < 8; ++k) s8 += tv[k];   // serial fp32 sum of 8
        const float dnm = s8 + 1e-8f;

        float wv = 0.0f;
#pragma unroll
        for (int k = 0; k < 8; ++k) if (ti[k] == lane) wv = tv[k] / dnm;

        const size_t grow = (size_t)rowBase + r0 + rr;
        wout[grow * 64 + lane] = wv;
#pragma unroll
        for (int k = 0; k < 8; ++k)
            if (lane == k) iout[grow * 8 + k] = (float)ti[k];
    }
}

extern "C" void kernel_launch(void* const* d_in, const int* in_sizes, int n_in,
                              void* d_out, int out_size, void* d_ws, size_t ws_size,
                              hipStream_t stream)
{
    (void)n_in; (void)out_size;
    const float* x   = (const float*)d_in[0];
    const float* W1  = (const float*)d_in[1];
    const float* b1  = (const float*)d_in[2];
    const float* g1  = (const float*)d_in[3];
    const float* be1 = (const float*)d_in[4];
    const float* W2  = (const float*)d_in[5];
    const float* b2  = (const float*)d_in[6];
    const float* g2  = (const float*)d_in[7];
    const float* be2 = (const float*)d_in[8];

    const int B = in_sizes[0] / D_IN;
    float* wout = (float*)d_out;
    float* iout = wout + (size_t)B * E_OUT;
    float* hws  = (float*)d_ws;

    size_t cap = ws_size / ((size_t)H_MID * sizeof(float));
    long long ch = (long long)((cap > (size_t)B) ? (size_t)B : cap);
    ch &= ~127LL;
    if (ch < 128) ch = 128;
    const int CH = (int)ch;

    for (int base = 0; base < B; base += CH) {
        int Mc = B - base; if (Mc > CH) Mc = CH;
        dim3 grid1(H_MID / 128, Mc / 64);    // col-block fastest-varying
        gemm1_kernel<<<grid1, 256, 0, stream>>>(x + (size_t)base * D_IN, W1, hws);
        tail_v3_kernel<<<Mc / 8, 256, 0, stream>>>(hws, b1, g1, be1, W2, b2, g2, be2,
                                                   wout, iout, base);
    }
}